// Round 4
// baseline (259.586 us; speedup 1.0000x reference)
//
#include <hip/hip_runtime.h>
#include <math.h>

#define NB 64
#define NA 5
#define NC 80
#define HH 38
#define WW 38
#define HW (HH*WW)          // 1444
#define CELLS (NA*HW)       // 7220
#define NT 50
#define NCH 85
#define MBLK 29             // main blocks per batch: 29*256 = 7424 >= 7220
#define TOTBLK ((MBLK+1)*NB)

// ws layout (bytes 0..15 zeroed by hipMemsetAsync each launch):
//   ws[0] = main-loss accum, ws[1] = cls accum, ws[2] = n_obj accum, ws[3] = done counter (u32)

__constant__ float c_aw[NA] = {0.57273f, 1.87446f, 3.33843f, 7.88282f, 9.77052f};
__constant__ float c_ah[NA] = {0.677385f, 2.06253f, 5.47434f, 3.52778f, 9.16828f};

__global__ __launch_bounds__(256) void yolo_one(const float* __restrict__ pred,
                                                const float* __restrict__ tgt,
                                                float* __restrict__ ws,
                                                float* __restrict__ out) {
    const int b   = blockIdx.y;
    const int bx  = blockIdx.x;
    const int tid = threadIdx.x;

    __shared__ float s_gx[NT], s_gy[NT], s_gw[NT], s_gh[NT];
    __shared__ float s_tx[NT], s_ty[NT], s_tw[NT], s_th[NT];
    __shared__ int   s_cell[NT], s_cls[NT];
    __shared__ int   s_vc;
    __shared__ float s_red[4];

    // ---- prep: wave 0 derives the target table (parallel across lanes) ----
    if (tid < 64) {
        float cls = 0.f, cx = -1.f, cy = 0.f, wn = 0.f, hn = 0.f;
        if (tid < NT) {
            const float* tr = tgt + ((size_t)b*NT + tid)*5;
            cls = tr[0]; cx = tr[1]; cy = tr[2]; wn = tr[3]; hn = tr[4];
        }
        unsigned long long inv = __ballot(cx == -1.0f);   // lanes >= NT force bits set
        const int vc = (int)__ffsll(inv) - 1;
        if (tid == 0) s_vc = vc;
        if (tid < vc) {
            float gx = cx*WW, gy = cy*HH, gw = wn*WW, gh = hn*HH;
            int best = 0; float bi = -1.0f;
            #pragma unroll
            for (int a = 0; a < NA; ++a) {
                float inter = fminf(gw, c_aw[a]) * fminf(gh, c_ah[a]);
                float un = gw*gh + c_aw[a]*c_ah[a] - inter;
                float iou = (un > 0.f) ? inter/un : 0.f;
                if (iou > bi) { bi = iou; best = a; }      // first-max == jnp.argmax
            }
            int gi = (int)gx; gi = gi < 0 ? 0 : (gi > WW-1 ? WW-1 : gi);
            int gj = (int)gy; gj = gj < 0 ? 0 : (gj > HH-1 ? HH-1 : gj);
            s_gx[tid] = gx; s_gy[tid] = gy; s_gw[tid] = gw; s_gh[tid] = gh;
            s_tx[tid] = gx - (float)gi; s_ty[tid] = gy - (float)gj;
            // logf (not __logf) here: only ~670 lanes total, keep target math exact
            s_tw[tid] = logf(gw / c_aw[best]);
            s_th[tid] = logf(gh / c_ah[best]);
            s_cell[tid] = (best*HH + gj)*WW + gi;
            s_cls[tid]  = (int)cls;
        }
    }
    __syncthreads();
    const int vc = s_vc;

    if (bx < MBLK) {
        // ---------- main: conf + coord + noobj ----------
        float l = 0.f;
        const int cell = bx * 256 + tid;
        if (cell < CELLS) {
            const int a   = cell / HW;
            const int rem = cell - a*HW;
            const int j   = rem / WW;
            const int i   = rem - j*WW;
            const float* base = pred + ((size_t)(b*(NA*NCH) + a*NCH))*HW + rem;
            float p0 = base[0];
            float p1 = base[HW];
            float p2 = base[2*HW];
            float p3 = base[3*HW];
            float p4 = base[4*HW];
            float x    = 1.f/(1.f + __expf(-p0));
            float y    = 1.f/(1.f + __expf(-p1));
            float conf = 1.f/(1.f + __expf(-p4));
            float bxx = x + (float)i;
            float byy = y + (float)j;
            float bw = __expf(p2) * c_aw[a];
            float bh = __expf(p3) * c_ah[a];
            float hbw = bw*0.5f, hbh = bh*0.5f;
            float pa = bw*bh;

            float maxiou = 0.f, miou = 0.f;
            int match = -1;
            for (int t = 0; t < vc; ++t) {
                float gx = s_gx[t], gy = s_gy[t], gw = s_gw[t], gh = s_gh[t];
                float mx = fminf(bxx - hbw, gx - gw*0.5f);
                float Mx = fmaxf(bxx + hbw, gx + gw*0.5f);
                float my = fminf(byy - hbh, gy - gh*0.5f);
                float My = fmaxf(byy + hbh, gy + gh*0.5f);
                float cw  = bw + gw - (Mx - mx);
                float chh = bh + gh - (My - my);
                float inter = (cw > 0.f && chh > 0.f) ? cw*chh : 0.f;
                float un = pa + gw*gh - inter;
                float iou = (un > 0.f) ? inter/un : 0.f;
                maxiou = fmaxf(maxiou, iou);
                if (s_cell[t] == cell) { match = t; miou = iou; }  // last t wins
            }

            if (match >= 0) {
                float dx = x  - s_tx[match];
                float dy = y  - s_ty[match];
                float dw = p2 - s_tw[match];
                float dh = p3 - s_th[match];
                l += dx*dx + dy*dy + dw*dw + dh*dh;      // COORD_SCALE = 1
                float dc = conf - miou;
                l += 5.0f * dc*dc;                        // OBJ_SCALE = 5
            } else if (maxiou <= 0.6f) {
                l += conf*conf;                           // NOOBJ_SCALE = 1
            }
        }

        #pragma unroll
        for (int off = 32; off > 0; off >>= 1) l += __shfl_down(l, off, 64);
        if ((tid & 63) == 0) s_red[tid >> 6] = l;
        __syncthreads();
        if (tid == 0)
            atomicAdd(&ws[0], s_red[0]+s_red[1]+s_red[2]+s_red[3]);
    } else {
        // ---------- cls block: dedup + n_obj + class loss ----------
        const int lane = tid & 63;
        const int wv   = tid >> 6;

        __shared__ int s_act[NT];
        __shared__ float s_nobj;
        if (tid < 64) {
            int active = 0;
            if (tid < vc) {
                active = 1;
                const int mycell = s_cell[tid];
                for (int u = tid+1; u < vc; ++u)
                    if (s_cell[u] == mycell) { active = 0; break; }  // last-t-wins
                s_act[tid] = active;
            }
            unsigned long long am = __ballot(active != 0);
            if (tid == 0) s_nobj = (float)__popcll(am);
        }
        __syncthreads();

        float csum = 0.f;
        for (int t = wv; t < vc; t += 4) {
            if (!s_act[t]) continue;
            const int cell = s_cell[t];
            const int a = cell / HW, rem = cell - a*HW;
            const float* logit = pred + ((size_t)(b*(NA*NCH) + a*NCH) + 5)*HW + rem;
            float v0 = logit[(size_t)lane*HW];
            float v1 = (lane < NC-64) ? logit[(size_t)(lane+64)*HW] : -INFINITY;
            float m = fmaxf(v0, v1);
            #pragma unroll
            for (int off = 32; off > 0; off >>= 1) m = fmaxf(m, __shfl_xor(m, off, 64));
            const int tc = s_cls[t];
            float s  = __expf(v0 - m) + ((lane < NC-64) ? __expf(v1 - m) : 0.f);
            float tl = ((lane == tc) ? v0 : 0.f) + ((lane + 64 == tc) ? v1 : 0.f);
            #pragma unroll
            for (int off = 32; off > 0; off >>= 1) {
                s  += __shfl_xor(s,  off, 64);
                tl += __shfl_xor(tl, off, 64);
            }
            csum += (m + logf(s)) - tl;
        }
        if (lane == 0) s_red[wv] = csum;
        __syncthreads();
        if (tid == 0) {
            atomicAdd(&ws[1], s_red[0]+s_red[1]+s_red[2]+s_red[3]);
            atomicAdd(&ws[2], s_nobj);
        }
    }

    // ---------- last-block-done finalize (removes the fin_k launch) ----------
    if (tid == 0) {
        __threadfence();                                  // partials visible device-wide
        unsigned* cnt = (unsigned*)&ws[3];
        unsigned done = atomicAdd(cnt, 1u);
        if (done == (unsigned)(TOTBLK - 1)) {
            __threadfence();
            // atomicAdd(p, 0.f) => coherent L2 read of the final values
            float M  = atomicAdd(&ws[0], 0.0f);
            float Cs = atomicAdd(&ws[1], 0.0f);
            float Ns = atomicAdd(&ws[2], 0.0f);
            out[0] = M + Cs / fmaxf(Ns, 1.0f);
        }
    }
}

extern "C" void kernel_launch(void* const* d_in, const int* in_sizes, int n_in,
                              void* d_out, int out_size, void* d_ws, size_t ws_size,
                              hipStream_t stream) {
    const float* pred = (const float*)d_in[0];
    const float* tgt  = (const float*)d_in[1];
    float* ws  = (float*)d_ws;
    float* out = (float*)d_out;

    hipMemsetAsync(d_ws, 0, 16, stream);   // zero accumulators + done counter
    hipLaunchKernelGGL(yolo_one, dim3(MBLK+1, NB), dim3(256), 0, stream, pred, tgt, ws, out);
}

// Round 5
// 198.906 us; speedup vs baseline: 1.3051x; 1.3051x over previous
//
#include <hip/hip_runtime.h>
#include <math.h>

#define NB 64
#define NA 5
#define NC 80
#define HH 38
#define WW 38
#define HW (HH*WW)          // 1444
#define CELLS (NA*HW)       // 7220
#define NT 50
#define NCH 85
#define MBLK 29             // main blocks per batch: 29*256 = 7424 >= 7220

// ---- workspace layout (float element offsets); every slot written every launch ----
#define WS_PART 0                    // [NB*MBLK] per-main-block partial of coord+conf loss
#define WS_CLSP (NB*MBLK)            // [NB] per-batch class-loss sum
#define WS_NOBJ (NB*MBLK + NB)       // [NB] per-batch unique-obj count

__constant__ float c_aw[NA] = {0.57273f, 1.87446f, 3.33843f, 7.88282f, 9.77052f};
__constant__ float c_ah[NA] = {0.677385f, 2.06253f, 5.47434f, 3.52778f, 9.16828f};

__global__ __launch_bounds__(256) void yolo_fused(const float* __restrict__ pred,
                                                  const float* __restrict__ tgt,
                                                  float* __restrict__ ws) {
    const int b   = blockIdx.y;
    const int bx  = blockIdx.x;
    const int tid = threadIdx.x;

    __shared__ float s_gx[NT], s_gy[NT], s_gw[NT], s_gh[NT];
    __shared__ float s_tx[NT], s_ty[NT], s_tw[NT], s_th[NT];
    __shared__ int   s_cell[NT], s_cls[NT];
    __shared__ int   s_vc;
    __shared__ float s_red[4];

    // ---- prep: wave 0 derives the target table (parallel across lanes) ----
    if (tid < 64) {
        float cls = 0.f, cx = -1.f, cy = 0.f, wn = 0.f, hn = 0.f;
        if (tid < NT) {
            const float* tr = tgt + ((size_t)b*NT + tid)*5;
            cls = tr[0]; cx = tr[1]; cy = tr[2]; wn = tr[3]; hn = tr[4];
        }
        unsigned long long inv = __ballot(cx == -1.0f);   // lanes >= NT force bits set
        const int vc = (int)__ffsll(inv) - 1;
        if (tid == 0) s_vc = vc;
        if (tid < vc) {
            float gx = cx*WW, gy = cy*HH, gw = wn*WW, gh = hn*HH;
            int best = 0; float bi = -1.0f;
            #pragma unroll
            for (int a = 0; a < NA; ++a) {
                float inter = fminf(gw, c_aw[a]) * fminf(gh, c_ah[a]);
                float un = gw*gh + c_aw[a]*c_ah[a] - inter;
                float iou = (un > 0.f) ? inter/un : 0.f;
                if (iou > bi) { bi = iou; best = a; }      // first-max == jnp.argmax
            }
            int gi = (int)gx; gi = gi < 0 ? 0 : (gi > WW-1 ? WW-1 : gi);
            int gj = (int)gy; gj = gj < 0 ? 0 : (gj > HH-1 ? HH-1 : gj);
            s_gx[tid] = gx; s_gy[tid] = gy; s_gw[tid] = gw; s_gh[tid] = gh;
            s_tx[tid] = gx - (float)gi; s_ty[tid] = gy - (float)gj;
            // exact logf here: ~670 lanes total, keep target math bit-accurate
            s_tw[tid] = logf(gw / c_aw[best]);
            s_th[tid] = logf(gh / c_ah[best]);
            s_cell[tid] = (best*HH + gj)*WW + gi;
            s_cls[tid]  = (int)cls;
        }
    }
    __syncthreads();
    const int vc = s_vc;

    if (bx < MBLK) {
        // ---------- main: conf + coord + noobj ----------
        float l = 0.f;
        const int cell = bx * 256 + tid;
        if (cell < CELLS) {
            const int a   = cell / HW;
            const int rem = cell - a*HW;
            const int j   = rem / WW;
            const int i   = rem - j*WW;
            const float* base = pred + ((size_t)(b*(NA*NCH) + a*NCH))*HW + rem;
            float p0 = base[0];
            float p1 = base[HW];
            float p2 = base[2*HW];
            float p3 = base[3*HW];
            float p4 = base[4*HW];
            float x    = 1.f/(1.f + __expf(-p0));
            float y    = 1.f/(1.f + __expf(-p1));
            float conf = 1.f/(1.f + __expf(-p4));
            float bxx = x + (float)i;
            float byy = y + (float)j;
            float bw = __expf(p2) * c_aw[a];
            float bh = __expf(p3) * c_ah[a];
            float hbw = bw*0.5f, hbh = bh*0.5f;
            float pa = bw*bh;

            float maxiou = 0.f, miou = 0.f;
            int match = -1;
            for (int t = 0; t < vc; ++t) {
                float gx = s_gx[t], gy = s_gy[t], gw = s_gw[t], gh = s_gh[t];
                float mx = fminf(bxx - hbw, gx - gw*0.5f);
                float Mx = fmaxf(bxx + hbw, gx + gw*0.5f);
                float my = fminf(byy - hbh, gy - gh*0.5f);
                float My = fmaxf(byy + hbh, gy + gh*0.5f);
                float cw  = bw + gw - (Mx - mx);
                float chh = bh + gh - (My - my);
                float inter = (cw > 0.f && chh > 0.f) ? cw*chh : 0.f;
                float un = pa + gw*gh - inter;
                float iou = (un > 0.f) ? inter/un : 0.f;
                maxiou = fmaxf(maxiou, iou);
                if (s_cell[t] == cell) { match = t; miou = iou; }  // last t wins
            }

            if (match >= 0) {
                float dx = x  - s_tx[match];
                float dy = y  - s_ty[match];
                float dw = p2 - s_tw[match];
                float dh = p3 - s_th[match];
                l += dx*dx + dy*dy + dw*dw + dh*dh;      // COORD_SCALE = 1
                float dc = conf - miou;
                l += 5.0f * dc*dc;                        // OBJ_SCALE = 5
            } else if (maxiou <= 0.6f) {
                l += conf*conf;                           // NOOBJ_SCALE = 1
            }
        }

        #pragma unroll
        for (int off = 32; off > 0; off >>= 1) l += __shfl_down(l, off, 64);
        if ((tid & 63) == 0) s_red[tid >> 6] = l;
        __syncthreads();
        if (tid == 0)
            ws[WS_PART + b*MBLK + bx] = s_red[0]+s_red[1]+s_red[2]+s_red[3];
    } else {
        // ---------- cls block: dedup + n_obj + class loss ----------
        const int lane = tid & 63;
        const int wv   = tid >> 6;

        __shared__ int s_act[NT];
        __shared__ float s_nobj;
        if (tid < 64) {
            int active = 0;
            if (tid < vc) {
                active = 1;
                const int mycell = s_cell[tid];
                for (int u = tid+1; u < vc; ++u)
                    if (s_cell[u] == mycell) { active = 0; break; }  // last-t-wins
                s_act[tid] = active;
            }
            unsigned long long am = __ballot(active != 0);
            if (tid == 0) s_nobj = (float)__popcll(am);
        }
        __syncthreads();

        float csum = 0.f;
        for (int t = wv; t < vc; t += 4) {
            if (!s_act[t]) continue;
            const int cell = s_cell[t];
            const int a = cell / HW, rem = cell - a*HW;
            const float* logit = pred + ((size_t)(b*(NA*NCH) + a*NCH) + 5)*HW + rem;
            float v0 = logit[(size_t)lane*HW];
            float v1 = (lane < NC-64) ? logit[(size_t)(lane+64)*HW] : -INFINITY;
            float m = fmaxf(v0, v1);
            #pragma unroll
            for (int off = 32; off > 0; off >>= 1) m = fmaxf(m, __shfl_xor(m, off, 64));
            const int tc = s_cls[t];
            float s  = __expf(v0 - m) + ((lane < NC-64) ? __expf(v1 - m) : 0.f);
            float tl = ((lane == tc) ? v0 : 0.f) + ((lane + 64 == tc) ? v1 : 0.f);
            #pragma unroll
            for (int off = 32; off > 0; off >>= 1) {
                s  += __shfl_xor(s,  off, 64);
                tl += __shfl_xor(tl, off, 64);
            }
            csum += (m + logf(s)) - tl;
        }
        if (lane == 0) s_red[wv] = csum;
        __syncthreads();
        if (tid == 0) {
            ws[WS_CLSP + b] = s_red[0]+s_red[1]+s_red[2]+s_red[3];
            ws[WS_NOBJ + b] = s_nobj;
        }
    }
}

__global__ __launch_bounds__(256) void fin_k(const float* __restrict__ ws,
                                             float* __restrict__ out) {
    const int tid = threadIdx.x;
    __shared__ float s_red[4*3];
    float m = 0.f, c = 0.f, n = 0.f;
    for (int idx = tid; idx < NB*MBLK; idx += 256) m += ws[WS_PART + idx];
    if (tid < NB) { c = ws[WS_CLSP + tid]; n = ws[WS_NOBJ + tid]; }
    #pragma unroll
    for (int off = 32; off > 0; off >>= 1) {
        m += __shfl_down(m, off, 64);
        c += __shfl_down(c, off, 64);
        n += __shfl_down(n, off, 64);
    }
    const int wv = tid >> 6;
    if ((tid & 63) == 0) { s_red[wv*3] = m; s_red[wv*3+1] = c; s_red[wv*3+2] = n; }
    __syncthreads();
    if (tid == 0) {
        float M = 0.f, Cs = 0.f, Ns = 0.f;
        #pragma unroll
        for (int w = 0; w < 4; ++w) { M += s_red[w*3]; Cs += s_red[w*3+1]; Ns += s_red[w*3+2]; }
        out[0] = M + Cs / fmaxf(Ns, 1.0f);
    }
}

extern "C" void kernel_launch(void* const* d_in, const int* in_sizes, int n_in,
                              void* d_out, int out_size, void* d_ws, size_t ws_size,
                              hipStream_t stream) {
    const float* pred = (const float*)d_in[0];
    const float* tgt  = (const float*)d_in[1];
    float* ws  = (float*)d_ws;
    float* out = (float*)d_out;

    hipLaunchKernelGGL(yolo_fused, dim3(MBLK+1, NB), dim3(256), 0, stream, pred, tgt, ws);
    hipLaunchKernelGGL(fin_k, dim3(1), dim3(256), 0, stream, ws, out);
}